// Round 1
// baseline (905.480 us; speedup 1.0000x reference)
//
#include <hip/hip_runtime.h>
#include <stdint.h>

#define NN   100000
#define FIN  128
#define HIDN 64
#define NCLS 40
#define NE   1600000

// ---- edge dtype probe: int64 (odd u32 words all zero) vs int32 ----
__global__ __launch_bounds__(64) void probe_kernel(const unsigned int* __restrict__ raw,
                                                   int* __restrict__ flag) {
  if (threadIdx.x == 0) {
    int is64 = 1;
    for (int i = 0; i < 64; ++i)
      if (raw[2 * i + 1] != 0u) { is64 = 0; break; }
    *flag = is64;
  }
}

__global__ __launch_bounds__(256) void cvt_kernel(const void* __restrict__ eptr,
                                                  const int* __restrict__ flag,
                                                  int* __restrict__ src,
                                                  int* __restrict__ dst) {
  int e = blockIdx.x * 256 + threadIdx.x;
  if (*flag) {
    const long long* p = (const long long*)eptr;
    src[e] = (int)p[e];
    dst[e] = (int)p[e + NE];
  } else {
    const int* p = (const int*)eptr;
    src[e] = p[e];
    dst[e] = p[e + NE];
  }
}

// ---- degree (into dinv buffer), then dinv = rsqrt(deg+1) in place ----
__global__ __launch_bounds__(256) void deg_kernel(const int* __restrict__ dst,
                                                  float* __restrict__ deg) {
  int e = blockIdx.x * 256 + threadIdx.x;
  atomicAdd(&deg[dst[e]], 1.0f);
}

__global__ __launch_bounds__(256) void rsqrt_kernel(float* __restrict__ dinv) {
  int i = blockIdx.x * 256 + threadIdx.x;
  if (i < NN) dinv[i] = rsqrtf(dinv[i] + 1.0f);
}

// ---- GEMM1: h[N,64] = x[N,128] @ W1[128,64]; W in LDS, x in regs ----
// 256 thr: cg=tid&3 (16 cols), rp=tid>>2 (2 rows) -> 128 rows/block
__global__ __launch_bounds__(256) void gemm1_kernel(const float* __restrict__ x,
                                                    const float* __restrict__ W,
                                                    float* __restrict__ h) {
  __shared__ float sW[FIN * HIDN];  // 32 KB
  int tid = threadIdx.x;
  {
    const float4* W4 = (const float4*)W;
    float4* sW4 = (float4*)sW;
#pragma unroll
    for (int i = 0; i < 8; ++i) sW4[i * 256 + tid] = W4[i * 256 + tid];
  }
  __syncthreads();
  int cg = tid & 3;
  int rp = tid >> 2;
  int r0 = blockIdx.x * 128 + rp * 2;
  int r1 = r0 + 1;
  bool v0 = (r0 < NN), v1 = (r1 < NN);
  int c0 = cg * 16;
  float4 a0[4], a1[4];
#pragma unroll
  for (int j = 0; j < 4; ++j) {
    a0[j] = make_float4(0.f, 0.f, 0.f, 0.f);
    a1[j] = make_float4(0.f, 0.f, 0.f, 0.f);
  }
  const float4* x4 = (const float4*)x;
  const float4 z4 = make_float4(0.f, 0.f, 0.f, 0.f);
  for (int k0 = 0; k0 < FIN; k0 += 4) {
    float4 xa = v0 ? x4[(size_t)r0 * 32 + (k0 >> 2)] : z4;
    float4 xb = v1 ? x4[(size_t)r1 * 32 + (k0 >> 2)] : z4;
#pragma unroll
    for (int kk = 0; kk < 4; ++kk) {
      float xav = (&xa.x)[kk];
      float xbv = (&xb.x)[kk];
      int k = k0 + kk;
#pragma unroll
      for (int j = 0; j < 4; ++j) {
        float4 wv = *(const float4*)&sW[k * HIDN + c0 + 4 * j];
        a0[j].x += xav * wv.x; a0[j].y += xav * wv.y;
        a0[j].z += xav * wv.z; a0[j].w += xav * wv.w;
        a1[j].x += xbv * wv.x; a1[j].y += xbv * wv.y;
        a1[j].z += xbv * wv.z; a1[j].w += xbv * wv.w;
      }
    }
  }
  if (v0) {
    float4* hp = (float4*)&h[(size_t)r0 * HIDN + c0];
#pragma unroll
    for (int j = 0; j < 4; ++j) hp[j] = a0[j];
  }
  if (v1) {
    float4* hp = (float4*)&h[(size_t)r1 * HIDN + c0];
#pragma unroll
    for (int j = 0; j < 4; ++j) hp[j] = a1[j];
  }
}

// ---- agg1 init: agg = h*dinv^2 + b1 (self-loop term + bias) ----
__global__ __launch_bounds__(256) void init1_kernel(const float* __restrict__ h,
                                                    const float* __restrict__ dinv,
                                                    const float* __restrict__ b1,
                                                    float* __restrict__ agg) {
  int t = blockIdx.x * 256 + threadIdx.x;
  int i = t >> 6, c = t & 63;
  float di = dinv[i];
  agg[t] = h[t] * di * di + b1[c];
}

// ---- scatter layer 1: one wave per edge, 64 lanes = 64 cols ----
__global__ __launch_bounds__(256) void scatter1_kernel(const int* __restrict__ src,
                                                       const int* __restrict__ dst,
                                                       const float* __restrict__ dinv,
                                                       const float* __restrict__ h,
                                                       float* __restrict__ agg) {
  int wid = (blockIdx.x * 256 + threadIdx.x) >> 6;
  int lane = threadIdx.x & 63;
  int e0 = wid * 4;
#pragma unroll
  for (int i = 0; i < 4; ++i) {
    int e = e0 + i;
    int s = src[e], d = dst[e];
    float w = dinv[s] * dinv[d];
    float v = h[(size_t)s * HIDN + lane] * w;
    atomicAdd(&agg[(size_t)d * HIDN + lane], v);
  }
}

// ---- GEMM2: h2[N,40] = relu(agg)[N,64] @ W2[64,40] ----
// 320 thr: cg=tid%10 (4 cols), rp=tid/10 (2 rows) -> 64 rows/block
__global__ __launch_bounds__(320) void gemm2_kernel(const float* __restrict__ agg,
                                                    const float* __restrict__ W2,
                                                    float* __restrict__ h2) {
  __shared__ float sW[HIDN * NCLS];  // 10 KB
  int tid = threadIdx.x;
  for (int i = tid; i < (HIDN * NCLS) / 4; i += 320)
    ((float4*)sW)[i] = ((const float4*)W2)[i];
  __syncthreads();
  int cg = tid % 10;
  int rp = tid / 10;
  int r0 = blockIdx.x * 64 + rp * 2;
  int r1 = r0 + 1;
  bool v0 = (r0 < NN), v1 = (r1 < NN);
  int c0 = cg * 4;
  float4 a0 = make_float4(0.f, 0.f, 0.f, 0.f);
  float4 a1 = make_float4(0.f, 0.f, 0.f, 0.f);
  const float4* g4 = (const float4*)agg;
  const float4 z4 = make_float4(0.f, 0.f, 0.f, 0.f);
  for (int k0 = 0; k0 < HIDN; k0 += 4) {
    float4 xa = v0 ? g4[(size_t)r0 * 16 + (k0 >> 2)] : z4;
    float4 xb = v1 ? g4[(size_t)r1 * 16 + (k0 >> 2)] : z4;
    xa.x = fmaxf(xa.x, 0.f); xa.y = fmaxf(xa.y, 0.f);
    xa.z = fmaxf(xa.z, 0.f); xa.w = fmaxf(xa.w, 0.f);
    xb.x = fmaxf(xb.x, 0.f); xb.y = fmaxf(xb.y, 0.f);
    xb.z = fmaxf(xb.z, 0.f); xb.w = fmaxf(xb.w, 0.f);
#pragma unroll
    for (int kk = 0; kk < 4; ++kk) {
      float xav = (&xa.x)[kk];
      float xbv = (&xb.x)[kk];
      float4 wv = *(const float4*)&sW[(k0 + kk) * NCLS + c0];
      a0.x += xav * wv.x; a0.y += xav * wv.y; a0.z += xav * wv.z; a0.w += xav * wv.w;
      a1.x += xbv * wv.x; a1.y += xbv * wv.y; a1.z += xbv * wv.z; a1.w += xbv * wv.w;
    }
  }
  if (v0) *(float4*)&h2[(size_t)r0 * NCLS + c0] = a0;
  if (v1) *(float4*)&h2[(size_t)r1 * NCLS + c0] = a1;
}

// ---- out init: out = h2*dinv^2 + b2 ----
__global__ __launch_bounds__(256) void init2_kernel(const float* __restrict__ h2,
                                                    const float* __restrict__ dinv,
                                                    const float* __restrict__ b2,
                                                    float* __restrict__ out) {
  unsigned t = blockIdx.x * 256 + threadIdx.x;
  unsigned i = t / NCLS, c = t - i * NCLS;
  float di = dinv[i];
  out[t] = h2[t] * di * di + b2[c];
}

// ---- scatter layer 2: thread per (edge,col) ----
__global__ __launch_bounds__(256) void scatter2_kernel(const int* __restrict__ src,
                                                       const int* __restrict__ dst,
                                                       const float* __restrict__ dinv,
                                                       const float* __restrict__ h2,
                                                       float* __restrict__ out) {
  unsigned t = blockIdx.x * 256 + threadIdx.x;
  unsigned e = t / NCLS;
  unsigned c = t - e * NCLS;
  int s = src[e], d = dst[e];
  float w = dinv[s] * dinv[d];
  atomicAdd(&out[(size_t)d * NCLS + c], h2[(size_t)s * NCLS + c] * w);
}

extern "C" void kernel_launch(void* const* d_in, const int* in_sizes, int n_in,
                              void* d_out, int out_size, void* d_ws, size_t ws_size,
                              hipStream_t stream) {
  const float* x  = (const float*)d_in[0];
  const void*  ei = d_in[1];
  const float* W1 = (const float*)d_in[2];
  const float* b1 = (const float*)d_in[3];
  const float* W2 = (const float*)d_in[4];
  const float* b2 = (const float*)d_in[5];
  float* out = (float*)d_out;

  char* w = (char*)d_ws;
  size_t off = 0;
  auto carve = [&](size_t bytes) -> void* {
    void* p = w + off;
    off = (off + bytes + 255) & ~(size_t)255;
    return p;
  };
  int*   src  = (int*)  carve((size_t)NE * 4);
  int*   dstv = (int*)  carve((size_t)NE * 4);
  float* dinv = (float*)carve((size_t)NN * 4);
  int*   flag = (int*)  carve(256);
  float* hbuf = (float*)carve((size_t)NN * HIDN * 4);  // h1, then reused for h2
  float* agg  = (float*)carve((size_t)NN * HIDN * 4);

  probe_kernel<<<1, 64, 0, stream>>>((const unsigned int*)ei, flag);
  cvt_kernel<<<NE / 256, 256, 0, stream>>>(ei, flag, src, dstv);
  hipMemsetAsync(dinv, 0, (size_t)NN * 4, stream);
  deg_kernel<<<NE / 256, 256, 0, stream>>>(dstv, dinv);
  rsqrt_kernel<<<(NN + 255) / 256, 256, 0, stream>>>(dinv);
  gemm1_kernel<<<(NN + 127) / 128, 256, 0, stream>>>(x, W1, hbuf);
  init1_kernel<<<(NN * HIDN) / 256, 256, 0, stream>>>(hbuf, dinv, b1, agg);
  scatter1_kernel<<<NE / 16, 256, 0, stream>>>(src, dstv, dinv, hbuf, agg);
  gemm2_kernel<<<(NN + 63) / 64, 320, 0, stream>>>(agg, W2, hbuf);
  init2_kernel<<<(NN * NCLS) / 256, 256, 0, stream>>>(hbuf, dinv, b2, out);
  scatter2_kernel<<<(unsigned)(((size_t)NE * NCLS) / 256), 256, 0, stream>>>(src, dstv, dinv, hbuf, out);
}

// Round 2
// 560.990 us; speedup vs baseline: 1.6141x; 1.6141x over previous
//
#include <hip/hip_runtime.h>
#include <stdint.h>

#define NN   100000
#define FIN  128
#define HIDN 64
#define NCLS 40
#define NE   1600000
#define NB_SCAN ((NN + 255) / 256)   // 391 block sums

// ---- edge dtype probe: int64 (odd u32 words all zero) vs int32 ----
__global__ __launch_bounds__(64) void probe_kernel(const unsigned int* __restrict__ raw,
                                                   int* __restrict__ flag) {
  if (threadIdx.x == 0) {
    int is64 = 1;
    for (int i = 0; i < 64; ++i)
      if (raw[2 * i + 1] != 0u) { is64 = 0; break; }
    *flag = is64;
  }
}

__global__ __launch_bounds__(256) void cvt_kernel(const void* __restrict__ eptr,
                                                  const int* __restrict__ flag,
                                                  int* __restrict__ src,
                                                  int* __restrict__ dst) {
  int e = blockIdx.x * 256 + threadIdx.x;
  if (*flag) {
    const long long* p = (const long long*)eptr;
    src[e] = (int)p[e];
    dst[e] = (int)p[e + NE];
  } else {
    const int* p = (const int*)eptr;
    src[e] = p[e];
    dst[e] = p[e + NE];
  }
}

// ---- CSR build: histogram, scan, place ----
__global__ __launch_bounds__(256) void hist_kernel(const int* __restrict__ dst,
                                                   int* __restrict__ cnt) {
  int e = blockIdx.x * 256 + threadIdx.x;
  atomicAdd(&cnt[dst[e]], 1);
}

__global__ __launch_bounds__(256) void scan1_kernel(const int* __restrict__ cnt,
                                                    int* __restrict__ off,
                                                    int* __restrict__ bsum) {
  __shared__ int s[256];
  int i = blockIdx.x * 256 + threadIdx.x;
  int v = (i < NN) ? cnt[i] : 0;
  s[threadIdx.x] = v;
  __syncthreads();
#pragma unroll
  for (int d = 1; d < 256; d <<= 1) {
    int t = (threadIdx.x >= d) ? s[threadIdx.x - d] : 0;
    __syncthreads();
    s[threadIdx.x] += t;
    __syncthreads();
  }
  if (i < NN) off[i] = s[threadIdx.x] - v;  // exclusive
  if (threadIdx.x == 255) bsum[blockIdx.x] = s[255];
}

__global__ __launch_bounds__(512) void scan2_kernel(int* __restrict__ bsum) {
  __shared__ int s[512];
  int i = threadIdx.x;
  int v = (i < NB_SCAN) ? bsum[i] : 0;
  s[i] = v;
  __syncthreads();
#pragma unroll
  for (int d = 1; d < 512; d <<= 1) {
    int t = (i >= d) ? s[i - d] : 0;
    __syncthreads();
    s[i] += t;
    __syncthreads();
  }
  if (i < NB_SCAN) bsum[i] = s[i] - v;  // exclusive over block sums
}

// off[i] += bsum[block]; cursor = off; dinv = rsqrt(cnt+1); off[NN] = NE
__global__ __launch_bounds__(256) void scan3_kernel(const int* __restrict__ cnt,
                                                    const int* __restrict__ bsum,
                                                    int* __restrict__ off,
                                                    int* __restrict__ cursor,
                                                    float* __restrict__ dinv) {
  int i = blockIdx.x * 256 + threadIdx.x;
  if (i < NN) {
    int o = off[i] + bsum[blockIdx.x];
    off[i] = o;
    cursor[i] = o;
    dinv[i] = rsqrtf((float)cnt[i] + 1.0f);
  }
  if (i == 0) off[NN] = NE;
}

__global__ __launch_bounds__(256) void place_kernel(const int* __restrict__ src,
                                                    const int* __restrict__ dst,
                                                    const float* __restrict__ dinv,
                                                    int* __restrict__ cursor,
                                                    int* __restrict__ s_src,
                                                    float* __restrict__ s_w) {
  int e = blockIdx.x * 256 + threadIdx.x;
  int s = src[e], d = dst[e];
  int p = atomicAdd(&cursor[d], 1);
  s_src[p] = s;
  s_w[p] = dinv[s] * dinv[d];
}

// ---- GEMM1: h[N,64] = x[N,128] @ W1[128,64]; W in LDS, x in regs ----
__global__ __launch_bounds__(256) void gemm1_kernel(const float* __restrict__ x,
                                                    const float* __restrict__ W,
                                                    float* __restrict__ h) {
  __shared__ float sW[FIN * HIDN];  // 32 KB
  int tid = threadIdx.x;
  {
    const float4* W4 = (const float4*)W;
    float4* sW4 = (float4*)sW;
#pragma unroll
    for (int i = 0; i < 8; ++i) sW4[i * 256 + tid] = W4[i * 256 + tid];
  }
  __syncthreads();
  int cg = tid & 3;
  int rp = tid >> 2;
  int r0 = blockIdx.x * 128 + rp * 2;
  int r1 = r0 + 1;
  bool v0 = (r0 < NN), v1 = (r1 < NN);
  int c0 = cg * 16;
  float4 a0[4], a1[4];
#pragma unroll
  for (int j = 0; j < 4; ++j) {
    a0[j] = make_float4(0.f, 0.f, 0.f, 0.f);
    a1[j] = make_float4(0.f, 0.f, 0.f, 0.f);
  }
  const float4* x4 = (const float4*)x;
  const float4 z4 = make_float4(0.f, 0.f, 0.f, 0.f);
  for (int k0 = 0; k0 < FIN; k0 += 4) {
    float4 xa = v0 ? x4[(size_t)r0 * 32 + (k0 >> 2)] : z4;
    float4 xb = v1 ? x4[(size_t)r1 * 32 + (k0 >> 2)] : z4;
#pragma unroll
    for (int kk = 0; kk < 4; ++kk) {
      float xav = (&xa.x)[kk];
      float xbv = (&xb.x)[kk];
      int k = k0 + kk;
#pragma unroll
      for (int j = 0; j < 4; ++j) {
        float4 wv = *(const float4*)&sW[k * HIDN + c0 + 4 * j];
        a0[j].x += xav * wv.x; a0[j].y += xav * wv.y;
        a0[j].z += xav * wv.z; a0[j].w += xav * wv.w;
        a1[j].x += xbv * wv.x; a1[j].y += xbv * wv.y;
        a1[j].z += xbv * wv.z; a1[j].w += xbv * wv.w;
      }
    }
  }
  if (v0) {
    float4* hp = (float4*)&h[(size_t)r0 * HIDN + c0];
#pragma unroll
    for (int j = 0; j < 4; ++j) hp[j] = a0[j];
  }
  if (v1) {
    float4* hp = (float4*)&h[(size_t)r1 * HIDN + c0];
#pragma unroll
    for (int j = 0; j < 4; ++j) hp[j] = a1[j];
  }
}

// ---- agg layer 1: gather-reduce per (node,col); self-loop + bias fused ----
__global__ __launch_bounds__(256) void agg1_kernel(const int* __restrict__ off,
                                                   const int* __restrict__ s_src,
                                                   const float* __restrict__ s_w,
                                                   const float* __restrict__ h,
                                                   const float* __restrict__ dinv,
                                                   const float* __restrict__ b1,
                                                   float* __restrict__ agg) {
  int t = blockIdx.x * 256 + threadIdx.x;
  int n = t >> 6, c = t & 63;
  if (n >= NN) return;
  int j0 = off[n], j1 = off[n + 1];
  float di = dinv[n];
  float acc = h[(size_t)n * HIDN + c] * di * di + b1[c];
  int j = j0;
  for (; j + 1 < j1; j += 2) {
    int s0 = s_src[j], s1 = s_src[j + 1];
    float w0 = s_w[j], w1 = s_w[j + 1];
    acc += h[(size_t)s0 * HIDN + c] * w0;
    acc += h[(size_t)s1 * HIDN + c] * w1;
  }
  if (j < j1) acc += h[(size_t)s_src[j] * HIDN + c] * s_w[j];
  agg[(size_t)n * HIDN + c] = acc;
}

// ---- GEMM2: h2[N,40] = relu(agg)[N,64] @ W2[64,40] ----
__global__ __launch_bounds__(320) void gemm2_kernel(const float* __restrict__ agg,
                                                    const float* __restrict__ W2,
                                                    float* __restrict__ h2) {
  __shared__ float sW[HIDN * NCLS];  // 10 KB
  int tid = threadIdx.x;
  for (int i = tid; i < (HIDN * NCLS) / 4; i += 320)
    ((float4*)sW)[i] = ((const float4*)W2)[i];
  __syncthreads();
  int cg = tid % 10;
  int rp = tid / 10;
  int r0 = blockIdx.x * 64 + rp * 2;
  int r1 = r0 + 1;
  bool v0 = (r0 < NN), v1 = (r1 < NN);
  int c0 = cg * 4;
  float4 a0 = make_float4(0.f, 0.f, 0.f, 0.f);
  float4 a1 = make_float4(0.f, 0.f, 0.f, 0.f);
  const float4* g4 = (const float4*)agg;
  const float4 z4 = make_float4(0.f, 0.f, 0.f, 0.f);
  for (int k0 = 0; k0 < HIDN; k0 += 4) {
    float4 xa = v0 ? g4[(size_t)r0 * 16 + (k0 >> 2)] : z4;
    float4 xb = v1 ? g4[(size_t)r1 * 16 + (k0 >> 2)] : z4;
    xa.x = fmaxf(xa.x, 0.f); xa.y = fmaxf(xa.y, 0.f);
    xa.z = fmaxf(xa.z, 0.f); xa.w = fmaxf(xa.w, 0.f);
    xb.x = fmaxf(xb.x, 0.f); xb.y = fmaxf(xb.y, 0.f);
    xb.z = fmaxf(xb.z, 0.f); xb.w = fmaxf(xb.w, 0.f);
#pragma unroll
    for (int kk = 0; kk < 4; ++kk) {
      float xav = (&xa.x)[kk];
      float xbv = (&xb.x)[kk];
      float4 wv = *(const float4*)&sW[(k0 + kk) * NCLS + c0];
      a0.x += xav * wv.x; a0.y += xav * wv.y; a0.z += xav * wv.z; a0.w += xav * wv.w;
      a1.x += xbv * wv.x; a1.y += xbv * wv.y; a1.z += xbv * wv.z; a1.w += xbv * wv.w;
    }
  }
  if (v0) *(float4*)&h2[(size_t)r0 * NCLS + c0] = a0;
  if (v1) *(float4*)&h2[(size_t)r1 * NCLS + c0] = a1;
}

// ---- agg layer 2: gather-reduce per (node,col) into d_out ----
__global__ __launch_bounds__(256) void agg2_kernel(const int* __restrict__ off,
                                                   const int* __restrict__ s_src,
                                                   const float* __restrict__ s_w,
                                                   const float* __restrict__ h2,
                                                   const float* __restrict__ dinv,
                                                   const float* __restrict__ b2,
                                                   float* __restrict__ out) {
  unsigned t = blockIdx.x * 256 + threadIdx.x;
  unsigned n = t / NCLS;
  unsigned c = t - n * NCLS;
  if (n >= NN) return;
  int j0 = off[n], j1 = off[n + 1];
  float di = dinv[n];
  float acc = h2[(size_t)n * NCLS + c] * di * di + b2[c];
  int j = j0;
  for (; j + 1 < j1; j += 2) {
    int s0 = s_src[j], s1 = s_src[j + 1];
    float w0 = s_w[j], w1 = s_w[j + 1];
    acc += h2[(size_t)s0 * NCLS + c] * w0;
    acc += h2[(size_t)s1 * NCLS + c] * w1;
  }
  if (j < j1) acc += h2[(size_t)s_src[j] * NCLS + c] * s_w[j];
  out[(size_t)n * NCLS + c] = acc;
}

extern "C" void kernel_launch(void* const* d_in, const int* in_sizes, int n_in,
                              void* d_out, int out_size, void* d_ws, size_t ws_size,
                              hipStream_t stream) {
  const float* x  = (const float*)d_in[0];
  const void*  ei = d_in[1];
  const float* W1 = (const float*)d_in[2];
  const float* b1 = (const float*)d_in[3];
  const float* W2 = (const float*)d_in[4];
  const float* b2 = (const float*)d_in[5];
  float* out = (float*)d_out;

  char* w = (char*)d_ws;
  size_t off_b = 0;
  auto carve = [&](size_t bytes) -> void* {
    void* p = w + off_b;
    off_b = (off_b + bytes + 255) & ~(size_t)255;
    return p;
  };
  int*   e_src = (int*)  carve((size_t)NE * 4);
  int*   e_dst = (int*)  carve((size_t)NE * 4);
  int*   cnt   = (int*)  carve((size_t)NN * 4);
  int*   offs  = (int*)  carve((size_t)(NN + 1) * 4);
  int*   curs  = (int*)  carve((size_t)NN * 4);
  int*   bsum  = (int*)  carve(512 * 4);
  float* dinv  = (float*)carve((size_t)NN * 4);
  int*   flag  = (int*)  carve(256);
  int*   s_src = (int*)  carve((size_t)NE * 4);
  float* s_w   = (float*)carve((size_t)NE * 4);
  float* hbuf  = (float*)carve((size_t)NN * HIDN * 4);  // h1, then h2
  float* agg   = (float*)carve((size_t)NN * HIDN * 4);

  probe_kernel<<<1, 64, 0, stream>>>((const unsigned int*)ei, flag);
  cvt_kernel<<<NE / 256, 256, 0, stream>>>(ei, flag, e_src, e_dst);
  hipMemsetAsync(cnt, 0, (size_t)NN * 4, stream);
  hist_kernel<<<NE / 256, 256, 0, stream>>>(e_dst, cnt);
  scan1_kernel<<<NB_SCAN, 256, 0, stream>>>(cnt, offs, bsum);
  scan2_kernel<<<1, 512, 0, stream>>>(bsum);
  scan3_kernel<<<NB_SCAN, 256, 0, stream>>>(cnt, bsum, offs, curs, dinv);
  place_kernel<<<NE / 256, 256, 0, stream>>>(e_src, e_dst, dinv, curs, s_src, s_w);
  gemm1_kernel<<<(NN + 127) / 128, 256, 0, stream>>>(x, W1, hbuf);
  agg1_kernel<<<(NN * HIDN) / 256, 256, 0, stream>>>(offs, s_src, s_w, hbuf, dinv, b1, agg);
  gemm2_kernel<<<(NN + 63) / 64, 320, 0, stream>>>(agg, W2, hbuf);
  agg2_kernel<<<(NN * NCLS + 255) / 256, 256, 0, stream>>>(offs, s_src, s_w, hbuf, dinv, b2, out);
}